// Round 1
// baseline (48.248 us; speedup 1.0000x reference)
//
#include <hip/hip_runtime.h>
#include <math.h>

#define BIGF 1e9f

constexpr int BB = 2, CC = 4, DD = 64, HH = 64, WW = 64;
constexpr int HW   = HH * WW;      // 4096
constexpr int DHW  = DD * HW;      // 262144
constexpr int CDHW = CC * DHW;     // 1048576
constexpr int NTOT = BB * CDHW;    // 2097152

// ---------------------------------------------------------------------------
// Pass 1: along W, directly from integer targets, all 4 classes at once.
// d1[b,c,d,h,i] = min_{j : tgt[b,d,h,j]==c} (i-j)^2   (BIG if none)
// One wave per line; 4 lines per 256-thread block.
// ---------------------------------------------------------------------------
__global__ __launch_bounds__(256) void edt_pass_w(const int* __restrict__ tgt,
                                                  float* __restrict__ out) {
    __shared__ int tl[4][64];
    const int t    = threadIdx.x;
    const int lane = t & 63;
    const int ll   = t >> 6;
    const int line = blockIdx.x * 4 + ll;   // 0 .. B*D*H-1
    const int h = line & 63;
    const int d = (line >> 6) & 63;
    const int b = line >> 12;

    tl[ll][lane] = tgt[(size_t)line * 64 + lane];
    __syncthreads();

    float m0 = BIGF, m1 = BIGF, m2 = BIGF, m3 = BIGF;
    #pragma unroll
    for (int j = 0; j < 64; ++j) {
        const int   c    = tl[ll][j];          // wave-uniform broadcast read
        const float diff = (float)(lane - j);
        const float cost = diff * diff;
        m0 = fminf(m0, (c == 0) ? cost : BIGF);
        m1 = fminf(m1, (c == 1) ? cost : BIGF);
        m2 = fminf(m2, (c == 2) ? cost : BIGF);
        m3 = fminf(m3, (c == 3) ? cost : BIGF);
    }
    const size_t base = (size_t)b * CDHW + (size_t)d * HW + h * 64 + lane;
    out[base]           = m0;
    out[base +     DHW] = m1;
    out[base + 2 * DHW] = m2;
    out[base + 3 * DHW] = m3;
}

// ---------------------------------------------------------------------------
// Pass 2: along H, in place. One block per (b,c,d) slice (contiguous 64x64).
// Each thread owns a 4(i) x 4(w) register tile; each ds_read_b128 of 4 w's
// is reused across 4 i's.
// ---------------------------------------------------------------------------
__global__ __launch_bounds__(256) void edt_pass_h(float* __restrict__ buf) {
    __shared__ float sl[HW];
    const int t = threadIdx.x;
    const size_t base = (size_t)blockIdx.x * HW;

    #pragma unroll
    for (int k = 0; k < 16; ++k) sl[t + k * 256] = buf[base + t + k * 256];
    __syncthreads();

    const int wg = (t & 15) * 4;       // w offset (float4)
    const int i0 = (t >> 4) * 4;       // 4 consecutive output rows
    float acc[4][4];
    #pragma unroll
    for (int a = 0; a < 4; ++a)
        #pragma unroll
        for (int k = 0; k < 4; ++k) acc[a][k] = BIGF;

    #pragma unroll 8
    for (int j = 0; j < 64; ++j) {
        const float4 v = *reinterpret_cast<const float4*>(&sl[j * 64 + wg]);
        #pragma unroll
        for (int a = 0; a < 4; ++a) {
            const float diff = (float)(i0 + a - j);
            const float cost = diff * diff;
            acc[a][0] = fminf(acc[a][0], v.x + cost);
            acc[a][1] = fminf(acc[a][1], v.y + cost);
            acc[a][2] = fminf(acc[a][2], v.z + cost);
            acc[a][3] = fminf(acc[a][3], v.w + cost);
        }
    }
    #pragma unroll
    for (int a = 0; a < 4; ++a) {
        const float4 o = make_float4(acc[a][0], acc[a][1], acc[a][2], acc[a][3]);
        *reinterpret_cast<float4*>(&buf[base + (size_t)(i0 + a) * 64 + wg]) = o;
    }
}

// ---------------------------------------------------------------------------
// Pass 3: along D, in place. One block per (b,c,h) slice; rows strided by HW.
// ---------------------------------------------------------------------------
__global__ __launch_bounds__(256) void edt_pass_d(float* __restrict__ buf) {
    __shared__ float sl[DD * 64];
    const int t  = threadIdx.x;
    const int bc = blockIdx.x >> 6;
    const int h  = blockIdx.x & 63;
    const size_t base = (size_t)bc * DHW + (size_t)h * 64;

    const int w  = t & 63;
    const int r0 = t >> 6;
    #pragma unroll
    for (int k = 0; k < 16; ++k) {
        const int r = r0 + k * 4;
        sl[r * 64 + w] = buf[base + (size_t)r * HW + w];
    }
    __syncthreads();

    const int wg = (t & 15) * 4;
    const int i0 = (t >> 4) * 4;
    float acc[4][4];
    #pragma unroll
    for (int a = 0; a < 4; ++a)
        #pragma unroll
        for (int k = 0; k < 4; ++k) acc[a][k] = BIGF;

    #pragma unroll 8
    for (int j = 0; j < 64; ++j) {
        const float4 v = *reinterpret_cast<const float4*>(&sl[j * 64 + wg]);
        #pragma unroll
        for (int a = 0; a < 4; ++a) {
            const float diff = (float)(i0 + a - j);
            const float cost = diff * diff;
            acc[a][0] = fminf(acc[a][0], v.x + cost);
            acc[a][1] = fminf(acc[a][1], v.y + cost);
            acc[a][2] = fminf(acc[a][2], v.z + cost);
            acc[a][3] = fminf(acc[a][3], v.w + cost);
        }
    }
    #pragma unroll
    for (int a = 0; a < 4; ++a) {
        const float4 o = make_float4(acc[a][0], acc[a][1], acc[a][2], acc[a][3]);
        *reinterpret_cast<float4*>(&buf[base + (size_t)(i0 + a) * HW + wg]) = o;
    }
}

// ---------------------------------------------------------------------------
// Reduce: softmax over C=4 x sqrt(distsq), block partial sums (deterministic).
// ---------------------------------------------------------------------------
__global__ __launch_bounds__(256) void bl_reduce(const float* __restrict__ pred,
                                                 const float* __restrict__ dsq,
                                                 float* __restrict__ partial) {
    const int idx = blockIdx.x * 256 + threadIdx.x;   // 0 .. B*DHW-1
    const int b = idx >> 18;                          // DHW = 2^18
    const int s = idx & (DHW - 1);
    const size_t p = (size_t)b * CDHW + s;

    const float p0 = pred[p], p1 = pred[p + DHW],
                p2 = pred[p + 2 * DHW], p3 = pred[p + 3 * DHW];
    const float m  = fmaxf(fmaxf(p0, p1), fmaxf(p2, p3));
    const float e0 = __expf(p0 - m), e1 = __expf(p1 - m),
                e2 = __expf(p2 - m), e3 = __expf(p3 - m);
    const float zinv = 1.0f / (e0 + e1 + e2 + e3);
    const float d0 = sqrtf(dsq[p]),           d1 = sqrtf(dsq[p + DHW]),
                d2 = sqrtf(dsq[p + 2 * DHW]), d3 = sqrtf(dsq[p + 3 * DHW]);
    float v = (e0 * d0 + e1 * d1 + e2 * d2 + e3 * d3) * zinv;

    #pragma unroll
    for (int off = 32; off > 0; off >>= 1) v += __shfl_down(v, off, 64);

    __shared__ float wsum[4];
    if ((threadIdx.x & 63) == 0) wsum[threadIdx.x >> 6] = v;
    __syncthreads();
    if (threadIdx.x == 0)
        partial[blockIdx.x] = wsum[0] + wsum[1] + wsum[2] + wsum[3];
}

__global__ __launch_bounds__(256) void bl_final(const float* __restrict__ partial,
                                                float* __restrict__ out, int n) {
    __shared__ double sd[256];
    double s = 0.0;
    for (int i = threadIdx.x; i < n; i += 256) s += (double)partial[i];
    sd[threadIdx.x] = s;
    __syncthreads();
    for (int str = 128; str > 0; str >>= 1) {
        if (threadIdx.x < str) sd[threadIdx.x] += sd[threadIdx.x + str];
        __syncthreads();
    }
    if (threadIdx.x == 0) out[0] = (float)(sd[0] / (double)NTOT);
}

// ---------------------------------------------------------------------------
extern "C" void kernel_launch(void* const* d_in, const int* in_sizes, int n_in,
                              void* d_out, int out_size, void* d_ws, size_t ws_size,
                              hipStream_t stream) {
    const float* pred = (const float*)d_in[0];
    const int*   tgt  = (const int*)d_in[1];
    float* out     = (float*)d_out;
    float* bufA    = (float*)d_ws;           // NTOT floats (8 MB)
    float* partial = bufA + NTOT;            // 2048 floats

    const int nredblk = BB * DHW / 256;      // 2048

    hipLaunchKernelGGL(edt_pass_w, dim3(BB * DD * HH / 4), dim3(256), 0, stream, tgt, bufA);
    hipLaunchKernelGGL(edt_pass_h, dim3(BB * CC * DD),     dim3(256), 0, stream, bufA);
    hipLaunchKernelGGL(edt_pass_d, dim3(BB * CC * HH),     dim3(256), 0, stream, bufA);
    hipLaunchKernelGGL(bl_reduce,  dim3(nredblk),          dim3(256), 0, stream, pred, bufA, partial);
    hipLaunchKernelGGL(bl_final,   dim3(1),                dim3(256), 0, stream, partial, out, nredblk);
}